// Round 5
// baseline (322.264 us; speedup 1.0000x reference)
//
#include <hip/hip_runtime.h>
#include <math.h>

// ============================================================================
// Sizes (fixed): N=2, C=64, Hax=56, W=56 -> B=112, H=56, OUT=64, N_HASHES=4,
// CHUNK=25, GROUPS=8, GP=8, hash_buckets=2, padding=19, K=3, qkv ch=96.
// Inputs fp32; OUTPUT FP32; stable argsort (established R8-R11).
// R17: 154.5us, k3=55.5. Bank conflicts measured irrelevant (0.7% of cycles).
// R18: (a) k0 transpose x->xT[n][h][w][c] (lives in Rb slot, dead until k3)
//      so k12 staging is coalesced float4 (was 224B-strided scalar = 64
//      lines/inst). (b) k3: no WbK/fold -- gather writes folded WcF =
//      v/|v| + 0.1we and nrm[8][25]; DI/main reconstruct raw wb =
//      (WcF-0.1we)*nrm (raw-dot = dotF - emb); bs l2norm over g fused here
//      via 3x shfl_xor -> writes bsn[112][300]; bsb buffer gone; LDS
//      40.4->37.1KB, one less barrier, ibL unioned into DIT. (c) k45: 512
//      threads, D-pass 1 row/thread, no bs-pass.
// R19: identical resubmit (R18 bench failed on container infra, no verdict).
//
// ws layout (float slots):
//   qkv : [112][5376]   off 0
//   bsn : [112][300]    off 602112  (old bsb slot)
//   Rb  : [112][38400]  off 870912  (xT[2][56][56][64] aliases this pre-k3)
//   idx : [112][224]    off 5171712 (int)
// ============================================================================

#define EPSN 5e-5f
#define INV_EPSN 20000.0f
#define LOG2E 1.4426950408889634f
#define LN2   0.6931471805599453f

__device__ __forceinline__ float dot4(const float4 a, const float4 b) {
    return a.x * b.x + a.y * b.y + a.z * b.z + a.w * b.w;
}
__device__ __forceinline__ void fma4(float4& a, float s, const float4 v) {
    a.x += s * v.x; a.y += s * v.y; a.z += s * v.z; a.w += s * v.w;
}

// ---------------- K0: x[n][c][h][w] -> xT[n][h][w][c] (LDS transpose) ------
__global__ __launch_bounds__(256) void k0_xT(
        const float* __restrict__ x, float* __restrict__ xT) {
    __shared__ float T[64][57];                 // pad 57: conflict-free read
    const int n = blockIdx.x, h = blockIdx.y, tid = threadIdx.x;
    const float* xb = x + n * 200704 + h * 56;
    #pragma unroll 7
    for (int i = tid; i < 3584; i += 256) {     // lanes: consecutive w
        int c = i / 56, w = i % 56;
        T[c][w] = xb[c * 3136 + w];
    }
    __syncthreads();
    float* xo = xT + n * 200704 + h * 3584;
    #pragma unroll 7
    for (int i = tid; i < 3584; i += 256) {     // lanes: consecutive c
        int w = i / 64, c = i % 64;
        xo[w * 64 + c] = T[c][w];
    }
}

// ---------------- K12: qkv GEMM + BN + LSH codes + stable argsort ----------
// Staging now reads xT coalesced (float4). o-quad register tile.
__global__ __launch_bounds__(256) void k12_qkv_sort(
        const float* __restrict__ xT, const float* __restrict__ cw,
        const float* __restrict__ gamma, const float* __restrict__ beta,
        const float* __restrict__ rot, float* __restrict__ qkv,
        int* __restrict__ idx_buf) {
    __shared__ float xsT[56 * 68];   // [h][c], pad 64->68
    __shared__ float cws[96 * 64];
    __shared__ float wm[56 * 32];    // w_match[t][f]
    __shared__ float rl[128];
    __shared__ float gs[96], bt[96];
    __shared__ int code[224];
    __shared__ int srt[224];
    const int b = blockIdx.x, n = b / 56, w = b % 56, tid = threadIdx.x;
    const float* xTb = xT + n * 200704 + w * 64;
    #pragma unroll 4
    for (int i = tid; i < 896; i += 256) {      // coalesced float4 rows
        int h = i / 16, cq = i % 16;
        *(float4*)&xsT[h * 68 + cq * 4] =
            *(const float4*)&xTb[h * 3584 + cq * 4];
    }
    #pragma unroll 8
    for (int i = tid; i < 6144; i += 256) cws[i] = cw[i];
    if (tid < 128) rl[tid] = rot[tid];
    if (tid < 96) { gs[tid] = gamma[tid]; bt[tid] = beta[tid]; }
    __syncthreads();
    const float inv_s = 1.0f / sqrtf(1.0f + 1.0e-5f);
    for (int tl = tid; tl < 1344; tl += 256) {
        int oq = tl / 56, h = tl % 56;
        int o0 = oq * 4;
        float s0 = 0.f, s1 = 0.f, s2 = 0.f, s3 = 0.f;
        #pragma unroll
        for (int cs = 0; cs < 16; ++cs) {
            float4 xv = *(const float4*)&xsT[h * 68 + cs * 4];
            float4 c0 = *(const float4*)&cws[(o0 + 0) * 64 + cs * 4];
            float4 c1 = *(const float4*)&cws[(o0 + 1) * 64 + cs * 4];
            float4 c2 = *(const float4*)&cws[(o0 + 2) * 64 + cs * 4];
            float4 c3 = *(const float4*)&cws[(o0 + 3) * 64 + cs * 4];
            s0 += dot4(xv, c0); s1 += dot4(xv, c1);
            s2 += dot4(xv, c2); s3 += dot4(xv, c3);
        }
        #pragma unroll
        for (int qq = 0; qq < 4; ++qq) {
            int o = o0 + qq;
            float sv = (qq == 0) ? s0 : (qq == 1) ? s1 : (qq == 2) ? s2 : s3;
            float val = sv * inv_s * gs[o] + bt[o];
            int j = o * 56 + h;
            qkv[b * 5376 + j] = val;
            int f = j % 96;                      // raw (B,96,56)->(B,56,96)
            if (f < 32) wm[(j / 96) * 32 + f] = val;
        }
    }
    __syncthreads();
    if (tid < 224) {
        int u = tid / 56, t = tid % 56;
        float s = 0.f;
        #pragma unroll 8
        for (int f = 0; f < 32; ++f) s += wm[t * 32 + f] * rl[f * 4 + u];
        code[tid] = ((s < 0.f) ? 1 : 0) + 2 * u;
    }
    __syncthreads();
    if (tid < 224) {
        int c = code[tid], r = 0;
        #pragma unroll 8
        for (int p = 0; p < 224; ++p) {
            int cp = code[p];
            r += (int)((cp < c) | ((cp == c) & (p < tid)));  // stable rank
        }
        srt[r] = tid;
    }
    __syncthreads();
    if (tid < 224) idx_buf[b * 224 + tid] = srt[tid];
}

// ---------------- K3: chunked attention, one block per (b,u,k) -------------
// gather(WcF folded + nrm, Vb) -> DI (reconstruct wb, DIT[j][i]) -> main
// (single-pass, no max: |ss|<=sqrt(2)) + fused bs-l2norm-over-g -> bsn.
// LDS 37.1KB -> 4 blocks/CU. ibL aliases DIT (dead after gather).
__global__ __launch_bounds__(256) void k3_attn(
        const float* __restrict__ qkv, const int* __restrict__ idx_buf,
        const float* __restrict__ rel, float* __restrict__ Rb,
        float* __restrict__ bsnW) {
    __shared__ __align__(16) float WcF[8][3][25][4];  // v/|v| + 0.1*we
    __shared__ __align__(16) float Vb[8][3][25][8];
    __shared__ float nrm[8][25];                      // |v| at kk==k
    __shared__ __align__(16) float DIT[75][25];       // inv-norm (ibL early)
    int* ibL = (int*)&DIT[0][0];
    const int b = blockIdx.x, u = blockIdx.y, k = blockIdx.z;
    const int tid = threadIdx.x;
    const float* q = qkv + b * 5376;

    if (tid < 224) ibL[tid] = idx_buf[b * 224 + tid];
    __syncthreads();

    #pragma unroll 3
    for (int idx = tid; idx < 600; idx += 256) {
        int i = idx % 25, kk = (idx / 25) % 3, g = idx / 75;
        int p0 = 1200 * g + 300 * u + 100 * kk + 4 * i;
        int h = p0 / 2400, r = p0 % 2400, t = r >> 5, f = r & 31;
        int row = (t < 56) ? t : t - 19;
        int tt = ibL[h * 56 + row] % 56;
        float4 v = *(const float4*)&q[tt * 96 + f];
        float len = fmaxf(sqrtf(dot4(v, v)), EPSN);
        float ni = 1.0f / len;
        int tw = kk * 25 + i, roww = (tw < 56) ? tw : tw - 19;
        float4 we = *(const float4*)&rel[roww * 12];
        float4 o;
        o.x = v.x * ni + 0.1f * we.x; o.y = v.y * ni + 0.1f * we.y;
        o.z = v.z * ni + 0.1f * we.z; o.w = v.w * ni + 0.1f * we.w;
        *(float4*)&WcF[g][kk][i][0] = o;
        if (kk == k) nrm[g][i] = len;
    }
    #pragma unroll 5
    for (int idx = tid; idx < 1200; idx += 256) {
        int half = idx & 1, fr = idx >> 1;
        int i = fr % 25, kk = (fr / 25) % 3, g = fr / 75;
        int p0 = 2400 * g + 600 * u + 200 * kk + 8 * i + 4 * half;
        int h = p0 / 4800, r = p0 % 4800, t = r >> 6, f = r & 63;
        int row = (t < 56) ? t : t - 19;
        int tt = ibL[h * 56 + row] % 56;
        *(float4*)&Vb[g][kk][i][4 * half] = *(const float4*)&q[tt * 96 + 32 + f];
    }
    __syncthreads();                              // ibL dead; DIT may be written

    // DI phase: 250 threads x 8 j's; wb reconstructed = (WcF-0.1we)*nrm.
    if (tid < 250) {
        const int i = tid % 25, jg = tid / 25;
        const int twi = k * 25 + i;
        const int rowwi = (twi < 56) ? twi : twi - 19;
        const float4 wei = *(const float4*)&rel[rowwi * 12];
        float4 wb8[8];
        #pragma unroll
        for (int g = 0; g < 8; ++g) {
            float4 t = *(const float4*)&WcF[g][k][i][0];
            float nr = nrm[g][i];
            wb8[g].x = (t.x - 0.1f * wei.x) * nr;
            wb8[g].y = (t.y - 0.1f * wei.y) * nr;
            wb8[g].z = (t.z - 0.1f * wei.z) * nr;
            wb8[g].w = (t.w - 0.1f * wei.w) * nr;
        }
        #pragma unroll
        for (int it = 0; it < 8; ++it) {
            int j = jg * 8 + it;
            if (j < 75) {
                int ks = j / 25, jj = j % 25;
                int roww = (j < 56) ? j : j - 19;
                float4 wej = *(const float4*)&rel[roww * 12];
                float s2 = 0.f;
                #pragma unroll
                for (int g = 0; g < 8; ++g) {
                    float dF = dot4(wb8[g], *(const float4*)&WcF[g][ks][jj][0]);
                    float emb = 0.1f * dot4(wb8[g], wej);
                    float raw = dF - emb;
                    s2 += raw * raw + emb * emb;
                }
                DIT[j][i] = fminf(__builtin_amdgcn_rsqf(s2), INV_EPSN);
            }
        }
    }
    __syncthreads();

    if (tid < 200) {
        const int g = tid & 7, i = tid >> 3;
        const int twi = k * 25 + i;
        const int rowwi = (twi < 56) ? twi : twi - 19;
        const float4 wei = *(const float4*)&rel[rowwi * 12];
        float4 wbr;
        {
            float4 t = *(const float4*)&WcF[g][k][i][0];
            float nr = nrm[g][i];
            wbr.x = (t.x - 0.1f * wei.x) * nr;
            wbr.y = (t.y - 0.1f * wei.y) * nr;
            wbr.z = (t.z - 0.1f * wei.z) * nr;
            wbr.w = (t.w - 0.1f * wei.w) * nr;
        }
        float se = 0.f;
        float4 a0 = {0,0,0,0}, a1 = {0,0,0,0}, a2 = {0,0,0,0}, a3 = {0,0,0,0};
        #pragma unroll
        for (int ks = 0; ks < 3; ++ks) {
            #pragma unroll
            for (int jj = 0; jj < 25; ++jj) {
                const int jP = ks * 25 + jj;                  // static
                const int roww = (jP < 56) ? jP : jP - 19;    // static
                float e = __builtin_amdgcn_exp2f(
                    dot4(wbr, *(const float4*)&WcF[g][ks][jj][0])
                    * DIT[jP][i] * LOG2E);
                se += e;
                const float4* vv = (const float4*)&Vb[g][ks][jj][0];
                fma4(a0, e, vv[0]); fma4(a1, e, vv[1]);
                float4 ve0 = *(const float4*)&rel[roww * 12 + 4];
                float4 ve1 = *(const float4*)&rel[roww * 12 + 8];
                fma4(a2, e, ve0); fma4(a3, e, ve1);
            }
        }
        // fused bs l2norm over g (pure g-axis -> 3x shfl_xor on lanes&7)
        float bs = __builtin_amdgcn_logf(se) * LN2;
        float s1 = bs, s2 = bs * bs;
        s1 += __shfl_xor(s1, 1); s2 += __shfl_xor(s2, 1);
        s1 += __shfl_xor(s1, 2); s2 += __shfl_xor(s2, 2);
        s1 += __shfl_xor(s1, 4); s2 += __shfl_xor(s2, 4);
        if (g == 0)
            bsnW[b * 300 + u * 75 + k * 25 + i] = s1 / fmaxf(sqrtf(s2), EPSN);
        const float rinv = 1.0f / se;
        const float r2 = 0.1f * rinv;            // F_GV1
        a0.x *= rinv; a0.y *= rinv; a0.z *= rinv; a0.w *= rinv;
        a1.x *= rinv; a1.y *= rinv; a1.z *= rinv; a1.w *= rinv;
        a2.x *= r2;   a2.y *= r2;   a2.z *= r2;   a2.w *= r2;
        a3.x *= r2;   a3.y *= r2;   a3.z *= r2;   a3.w *= r2;
        float* rp = Rb + b * 38400 + 4800 * g + 1200 * u + 400 * k + 16 * i;
        ((float4*)rp)[0] = a0;
        ((float4*)rp)[1] = a1;
        ((float4*)rp)[2] = a2;
        ((float4*)rp)[3] = a3;
    }
}

// ---------------- K45: channel l2norm + unsort + hash softmax + store ------
// 512 threads; D-pass 1 row/thread; bsn precomputed by k3. Split (b, o-half).
__global__ __launch_bounds__(512) void k45_post(
        const float* __restrict__ Rb, const float* __restrict__ bsnW,
        const int* __restrict__ idx_buf, float* __restrict__ out) {
    __shared__ float D[300];
    __shared__ float retU[224][32];
    __shared__ float bsU[224];
    __shared__ int idxL[224];
    const int b = blockIdx.x, oh = blockIdx.y, tid = threadIdx.x;
    const int n = b / 56, w = b % 56, o0 = oh * 32;
    const float* R = Rb + b * 38400;
    if (tid < 224) idxL[tid] = idx_buf[b * 224 + tid];
    if (tid < 300) {
        float s = 0.f;
        #pragma unroll 16
        for (int c = 0; c < 128; ++c) { float v = R[c * 300 + tid]; s += v * v; }
        D[tid] = fminf(__builtin_amdgcn_rsqf(s), INV_EPSN);
    }
    __syncthreads();
    if (tid < 224) {
        int u3 = tid / 56, t = tid % 56;
        bsU[idxL[tid]] = bsnW[b * 300 + u3 * 75 + t];
    }
    #pragma unroll 4
    for (int idx = tid; idx < 224 * 32; idx += 512) {
        int p = idx >> 5, oc = idx & 31;
        int o = o0 + oc;
        int u3 = p / 56, t = p % 56;
        int k3 = t / 25, i3 = t % 25;
        int q0 = 9600 * u3 + 3200 * k3 + 128 * i3 + 2 * o;
        float2 rv = *(const float2*)&R[q0];
        int r0 = q0 % 300;                       // q0 even => r0+1 never wraps
        float val = rv.x * D[r0] + rv.y * D[r0 + 1];
        retU[idxL[p]][oc] = val;
    }
    __syncthreads();
    for (int idx = tid; idx < 56 * 32; idx += 512) {
        int h = idx >> 5, oc = idx & 31;
        int o = o0 + oc;
        float b0 = bsU[h], b1 = bsU[56 + h], b2 = bsU[112 + h], b3 = bsU[168 + h];
        float m = fmaxf(fmaxf(b0, b1), fmaxf(b2, b3));
        float e0 = __builtin_amdgcn_exp2f((b0 - m) * LOG2E);
        float e1 = __builtin_amdgcn_exp2f((b1 - m) * LOG2E);
        float e2 = __builtin_amdgcn_exp2f((b2 - m) * LOG2E);
        float e3 = __builtin_amdgcn_exp2f((b3 - m) * LOG2E);
        float ps = e0 + e1 + e2 + e3;
        float val = (retU[h][oc] * e0 + retU[56 + h][oc] * e1 +
                     retU[112 + h][oc] * e2 + retU[168 + h][oc] * e3) / ps;
        out[((n * 64 + o) * 56 + h) * 56 + w] = val;   // (n,o,h,w)
    }
}

extern "C" void kernel_launch(void* const* d_in, const int* in_sizes, int n_in,
                              void* d_out, int out_size, void* d_ws, size_t ws_size,
                              hipStream_t stream) {
    (void)in_sizes; (void)n_in; (void)out_size; (void)ws_size;
    const float* x     = (const float*)d_in[0];
    const float* cw    = (const float*)d_in[1];
    const float* gamma = (const float*)d_in[2];
    const float* beta  = (const float*)d_in[3];
    const float* rel   = (const float*)d_in[4];
    const float* rot   = (const float*)d_in[5];
    float* ws  = (float*)d_ws;
    float* qkv = ws;
    float* bsn = ws + 602112;
    float* Rb  = ws + 870912;
    float* xT  = Rb;                 // aliases Rb; dead once k3 writes Rb
    int*   idx = (int*)(ws + 5171712);

    k0_xT<<<dim3(2, 56), 256, 0, stream>>>(x, xT);
    k12_qkv_sort<<<112, 256, 0, stream>>>(xT, cw, gamma, beta, rot, qkv, idx);
    k3_attn<<<dim3(112, 4, 3), 256, 0, stream>>>(qkv, idx, rel, Rb, bsn);
    k45_post<<<dim3(112, 2), 512, 0, stream>>>(Rb, bsn, idx, (float*)d_out);
}

// Round 6
// 150.715 us; speedup vs baseline: 2.1382x; 2.1382x over previous
//
#include <hip/hip_runtime.h>
#include <math.h>

// ============================================================================
// Sizes (fixed): N=2, C=64, Hax=56, W=56 -> B=112, H=56, OUT=64, N_HASHES=4,
// CHUNK=25, GROUPS=8, GP=8, hash_buckets=2, padding=19, K=3, qkv ch=96.
// Inputs fp32; OUTPUT FP32; stable argsort (established R8-R11).
// R17: 154.5us, k3=55.5 @ 88 VGPR (proven). R18/19: k3 restructure (folded
//      WcF + reconstruction + fused bs) -> VGPR 256 + catastrophic spill
//      (FETCH 156MB, WRITE 288MB, k3 233us). Rest-of-pipeline measured
//      89us (vs 99 in R17) -> k0/k12/k45 changes worth ~10us.
// R20: RECOVERY: k3 = R17 verbatim (writes bsb); keep k0 (x transpose) +
//      k12 (coalesced xT staging); k45 = split (b, o-half) x 512 thr with
//      bs-pass restored (reads bsb).
//
// ws layout (float slots):
//   qkv : [112][5376]   off 0
//   bsb : [112][2400]   off 602112
//   Rb  : [112][38400]  off 870912  (xT[2][56][56][64] aliases this pre-k3)
//   idx : [112][224]    off 5171712 (int)
// ============================================================================

#define EPSN 5e-5f
#define INV_EPSN 20000.0f
#define LOG2E 1.4426950408889634f
#define LN2   0.6931471805599453f

__device__ __forceinline__ float dot4(const float4 a, const float4 b) {
    return a.x * b.x + a.y * b.y + a.z * b.z + a.w * b.w;
}
__device__ __forceinline__ void fma4(float4& a, float s, const float4 v) {
    a.x += s * v.x; a.y += s * v.y; a.z += s * v.z; a.w += s * v.w;
}

// ---------------- K0: x[n][c][h][w] -> xT[n][h][w][c] (LDS transpose) ------
__global__ __launch_bounds__(256) void k0_xT(
        const float* __restrict__ x, float* __restrict__ xT) {
    __shared__ float T[64][57];                 // pad 57: conflict-free read
    const int n = blockIdx.x, h = blockIdx.y, tid = threadIdx.x;
    const float* xb = x + n * 200704 + h * 56;
    #pragma unroll 7
    for (int i = tid; i < 3584; i += 256) {     // lanes: consecutive w
        int c = i / 56, w = i % 56;
        T[c][w] = xb[c * 3136 + w];
    }
    __syncthreads();
    float* xo = xT + n * 200704 + h * 3584;
    #pragma unroll 7
    for (int i = tid; i < 3584; i += 256) {     // lanes: consecutive c
        int w = i / 64, c = i % 64;
        xo[w * 64 + c] = T[c][w];
    }
}

// ---------------- K12: qkv GEMM + BN + LSH codes + stable argsort ----------
// Staging reads xT coalesced (float4). o-quad register tile.
__global__ __launch_bounds__(256) void k12_qkv_sort(
        const float* __restrict__ xT, const float* __restrict__ cw,
        const float* __restrict__ gamma, const float* __restrict__ beta,
        const float* __restrict__ rot, float* __restrict__ qkv,
        int* __restrict__ idx_buf) {
    __shared__ float xsT[56 * 68];   // [h][c], pad 64->68
    __shared__ float cws[96 * 64];
    __shared__ float wm[56 * 32];    // w_match[t][f]
    __shared__ float rl[128];
    __shared__ float gs[96], bt[96];
    __shared__ int code[224];
    __shared__ int srt[224];
    const int b = blockIdx.x, n = b / 56, w = b % 56, tid = threadIdx.x;
    const float* xTb = xT + n * 200704 + w * 64;
    #pragma unroll 4
    for (int i = tid; i < 896; i += 256) {      // coalesced float4 rows
        int h = i / 16, cq = i % 16;
        *(float4*)&xsT[h * 68 + cq * 4] =
            *(const float4*)&xTb[h * 3584 + cq * 4];
    }
    #pragma unroll 8
    for (int i = tid; i < 6144; i += 256) cws[i] = cw[i];
    if (tid < 128) rl[tid] = rot[tid];
    if (tid < 96) { gs[tid] = gamma[tid]; bt[tid] = beta[tid]; }
    __syncthreads();
    const float inv_s = 1.0f / sqrtf(1.0f + 1.0e-5f);
    for (int tl = tid; tl < 1344; tl += 256) {
        int oq = tl / 56, h = tl % 56;
        int o0 = oq * 4;
        float s0 = 0.f, s1 = 0.f, s2 = 0.f, s3 = 0.f;
        #pragma unroll
        for (int cs = 0; cs < 16; ++cs) {
            float4 xv = *(const float4*)&xsT[h * 68 + cs * 4];
            float4 c0 = *(const float4*)&cws[(o0 + 0) * 64 + cs * 4];
            float4 c1 = *(const float4*)&cws[(o0 + 1) * 64 + cs * 4];
            float4 c2 = *(const float4*)&cws[(o0 + 2) * 64 + cs * 4];
            float4 c3 = *(const float4*)&cws[(o0 + 3) * 64 + cs * 4];
            s0 += dot4(xv, c0); s1 += dot4(xv, c1);
            s2 += dot4(xv, c2); s3 += dot4(xv, c3);
        }
        #pragma unroll
        for (int qq = 0; qq < 4; ++qq) {
            int o = o0 + qq;
            float sv = (qq == 0) ? s0 : (qq == 1) ? s1 : (qq == 2) ? s2 : s3;
            float val = sv * inv_s * gs[o] + bt[o];
            int j = o * 56 + h;
            qkv[b * 5376 + j] = val;
            int f = j % 96;                      // raw (B,96,56)->(B,56,96)
            if (f < 32) wm[(j / 96) * 32 + f] = val;
        }
    }
    __syncthreads();
    if (tid < 224) {
        int u = tid / 56, t = tid % 56;
        float s = 0.f;
        #pragma unroll 8
        for (int f = 0; f < 32; ++f) s += wm[t * 32 + f] * rl[f * 4 + u];
        code[tid] = ((s < 0.f) ? 1 : 0) + 2 * u;
    }
    __syncthreads();
    if (tid < 224) {
        int c = code[tid], r = 0;
        #pragma unroll 8
        for (int p = 0; p < 224; ++p) {
            int cp = code[p];
            r += (int)((cp < c) | ((cp == c) & (p < tid)));  // stable rank
        }
        srt[r] = tid;
    }
    __syncthreads();
    if (tid < 224) idx_buf[b * 224 + tid] = srt[tid];
}

// ---------------- K3: chunked attention (R17 verbatim, proven 55.5us) ------
// Phases: ibL stage -> gather/normalize -> DI phase (FMA-dense, DIT[j][i]) ->
// Wc += 0.1*we -> single-pass main (no max pass). LDS 40.4KB.
__global__ __launch_bounds__(256) void k3_attn(
        const float* __restrict__ qkv, const int* __restrict__ idx_buf,
        const float* __restrict__ rel, float* __restrict__ Rb,
        float* __restrict__ bsb) {
    __shared__ __align__(16) float Wc[8][3][25][4];   // normalized, then +0.1*we
    __shared__ __align__(16) float Vb[8][3][25][8];
    __shared__ __align__(16) float WbK[8][25][4];     // raw w_b at kk==k
    __shared__ float DIT[75][25];                     // transposed inv-norm
    __shared__ int ibL[224];
    const int b = blockIdx.x, u = blockIdx.y, k = blockIdx.z;
    const int tid = threadIdx.x;
    const float* q = qkv + b * 5376;

    if (tid < 224) ibL[tid] = idx_buf[b * 224 + tid];
    __syncthreads();

    #pragma unroll 3
    for (int idx = tid; idx < 600; idx += 256) {
        int i = idx % 25, kk = (idx / 25) % 3, g = idx / 75;
        int p0 = 1200 * g + 300 * u + 100 * kk + 4 * i;
        int h = p0 / 2400, r = p0 % 2400, t = r >> 5, f = r & 31;
        int row = (t < 56) ? t : t - 19;
        int tt = ibL[h * 56 + row] % 56;
        float4 v = *(const float4*)&q[tt * 96 + f];
        if (kk == k) *(float4*)&WbK[g][i][0] = v;
        float ni = fminf(__builtin_amdgcn_rsqf(dot4(v, v)), INV_EPSN);
        v.x *= ni; v.y *= ni; v.z *= ni; v.w *= ni;
        *(float4*)&Wc[g][kk][i][0] = v;
    }
    #pragma unroll 5
    for (int idx = tid; idx < 1200; idx += 256) {
        int half = idx & 1, fr = idx >> 1;
        int i = fr % 25, kk = (fr / 25) % 3, g = fr / 75;
        int p0 = 2400 * g + 600 * u + 200 * kk + 8 * i + 4 * half;
        int h = p0 / 4800, r = p0 % 4800, t = r >> 6, f = r & 63;
        int row = (t < 56) ? t : t - 19;
        int tt = ibL[h * 56 + row] % 56;
        *(float4*)&Vb[g][kk][i][4 * half] = *(const float4*)&q[tt * 96 + 32 + f];
    }
    __syncthreads();

    // DI phase: 250 threads x 8 j's each; register wb8; writes DIT[j][i].
    if (tid < 250) {
        const int i = tid % 25, jg = tid / 25;
        float4 wb8[8];
        #pragma unroll
        for (int g = 0; g < 8; ++g) wb8[g] = *(const float4*)&WbK[g][i][0];
        #pragma unroll
        for (int it = 0; it < 8; ++it) {
            int j = jg * 8 + it;
            if (j < 75) {
                int ks = j / 25, jj = j % 25;
                int roww = (j < 56) ? j : j - 19;
                float4 we = *(const float4*)&rel[roww * 12];
                we.x *= 0.1f; we.y *= 0.1f; we.z *= 0.1f; we.w *= 0.1f;
                float s2 = 0.f;
                #pragma unroll
                for (int g = 0; g < 8; ++g) {
                    float4 wcn = *(const float4*)&Wc[g][ks][jj][0];
                    float raw = dot4(wb8[g], wcn);
                    float emb = dot4(wb8[g], we);
                    s2 += raw * raw + emb * emb;
                }
                DIT[j][i] = fminf(__builtin_amdgcn_rsqf(s2), INV_EPSN);
            }
        }
    }
    __syncthreads();

    // Fold 0.1*we into Wc so main loop is one dot4 per (g,j).
    #pragma unroll 3
    for (int idx = tid; idx < 600; idx += 256) {
        int i = idx % 25, kk = (idx / 25) % 3, g = idx / 75;
        int tw = kk * 25 + i;
        int roww = (tw < 56) ? tw : tw - 19;
        float4 we = *(const float4*)&rel[roww * 12];
        float4 v = *(const float4*)&Wc[g][kk][i][0];
        v.x += 0.1f * we.x; v.y += 0.1f * we.y;
        v.z += 0.1f * we.z; v.w += 0.1f * we.w;
        *(float4*)&Wc[g][kk][i][0] = v;
    }
    __syncthreads();

    if (tid < 200) {
        const int g = tid & 7, i = tid >> 3;
        const float4 wbr = *(const float4*)&WbK[g][i][0];
        float se = 0.f;
        float4 a0 = {0,0,0,0}, a1 = {0,0,0,0}, a2 = {0,0,0,0}, a3 = {0,0,0,0};
        #pragma unroll
        for (int ks = 0; ks < 3; ++ks) {
            #pragma unroll
            for (int jj = 0; jj < 25; ++jj) {
                const int jP = ks * 25 + jj;                  // static
                const int roww = (jP < 56) ? jP : jP - 19;    // static
                float di = DIT[jP][i];
                float e = __builtin_amdgcn_exp2f(
                    dot4(wbr, *(const float4*)&Wc[g][ks][jj][0]) * di * LOG2E);
                se += e;
                const float4* vv = (const float4*)&Vb[g][ks][jj][0];
                fma4(a0, e, vv[0]); fma4(a1, e, vv[1]);
                float4 ve0 = *(const float4*)&rel[roww * 12 + 4];
                float4 ve1 = *(const float4*)&rel[roww * 12 + 8];
                fma4(a2, e, ve0); fma4(a3, e, ve1);
            }
        }
        bsb[b * 2400 + g * 300 + u * 75 + k * 25 + i] =
            __builtin_amdgcn_logf(se) * LN2;                  // logsumexp, no shift
        const float rinv = 1.0f / se;
        const float r2 = 0.1f * rinv;            // F_GV1
        a0.x *= rinv; a0.y *= rinv; a0.z *= rinv; a0.w *= rinv;
        a1.x *= rinv; a1.y *= rinv; a1.z *= rinv; a1.w *= rinv;
        a2.x *= r2;   a2.y *= r2;   a2.z *= r2;   a2.w *= r2;
        a3.x *= r2;   a3.y *= r2;   a3.z *= r2;   a3.w *= r2;
        float* rp = Rb + b * 38400 + 4800 * g + 1200 * u + 400 * k + 16 * i;
        ((float4*)rp)[0] = a0;
        ((float4*)rp)[1] = a1;
        ((float4*)rp)[2] = a2;
        ((float4*)rp)[3] = a3;
    }
}

// ---------------- K45: channel l2norm + bs-pass + unsort + hash softmax
//                        + transposed FP32 store. Split (b, o-half), 512 thr.
__global__ __launch_bounds__(512) void k45_post(
        const float* __restrict__ Rb, const float* __restrict__ bsb,
        const int* __restrict__ idx_buf, float* __restrict__ out) {
    __shared__ float D[300];
    __shared__ float bsn[300];
    __shared__ float retU[224][32];
    __shared__ float bsU[224];
    __shared__ int idxL[224];
    const int b = blockIdx.x, oh = blockIdx.y, tid = threadIdx.x;
    const int n = b / 56, w = b % 56, o0 = oh * 32;
    const float* R = Rb + b * 38400;
    if (tid < 224) idxL[tid] = idx_buf[b * 224 + tid];
    if (tid < 300) {
        float s = 0.f;
        #pragma unroll 16
        for (int c = 0; c < 128; ++c) { float v = R[c * 300 + tid]; s += v * v; }
        D[tid] = fminf(__builtin_amdgcn_rsqf(s), INV_EPSN);
    }
    if (tid >= 512 - 300 + 88) { }               // (no-op; keep shape simple)
    if (tid < 300) {
        int u = tid / 75, t = tid % 75;
        float s2 = 0.f, sum = 0.f;
        #pragma unroll
        for (int g = 0; g < 8; ++g) {
            float v = bsb[b * 2400 + g * 300 + u * 75 + t];
            s2 += v * v; sum += v;
        }
        bsn[tid] = sum / fmaxf(sqrtf(s2), EPSN);
    }
    __syncthreads();
    if (tid < 224) {
        int u3 = tid / 56, t = tid % 56;
        bsU[idxL[tid]] = bsn[u3 * 75 + t];
    }
    #pragma unroll 4
    for (int idx = tid; idx < 224 * 32; idx += 512) {
        int p = idx >> 5, oc = idx & 31;
        int o = o0 + oc;
        int u3 = p / 56, t = p % 56;
        int k3 = t / 25, i3 = t % 25;
        int q0 = 9600 * u3 + 3200 * k3 + 128 * i3 + 2 * o;
        float2 rv = *(const float2*)&R[q0];
        int r0 = q0 % 300;                       // q0 even => r0+1 never wraps
        float val = rv.x * D[r0] + rv.y * D[r0 + 1];
        retU[idxL[p]][oc] = val;
    }
    __syncthreads();
    for (int idx = tid; idx < 56 * 32; idx += 512) {
        int h = idx >> 5, oc = idx & 31;
        int o = o0 + oc;
        float b0 = bsU[h], b1 = bsU[56 + h], b2 = bsU[112 + h], b3 = bsU[168 + h];
        float m = fmaxf(fmaxf(b0, b1), fmaxf(b2, b3));
        float e0 = __builtin_amdgcn_exp2f((b0 - m) * LOG2E);
        float e1 = __builtin_amdgcn_exp2f((b1 - m) * LOG2E);
        float e2 = __builtin_amdgcn_exp2f((b2 - m) * LOG2E);
        float e3 = __builtin_amdgcn_exp2f((b3 - m) * LOG2E);
        float ps = e0 + e1 + e2 + e3;
        float val = (retU[h][oc] * e0 + retU[56 + h][oc] * e1 +
                     retU[112 + h][oc] * e2 + retU[168 + h][oc] * e3) / ps;
        out[((n * 64 + o) * 56 + h) * 56 + w] = val;   // (n,o,h,w)
    }
}

extern "C" void kernel_launch(void* const* d_in, const int* in_sizes, int n_in,
                              void* d_out, int out_size, void* d_ws, size_t ws_size,
                              hipStream_t stream) {
    (void)in_sizes; (void)n_in; (void)out_size; (void)ws_size;
    const float* x     = (const float*)d_in[0];
    const float* cw    = (const float*)d_in[1];
    const float* gamma = (const float*)d_in[2];
    const float* beta  = (const float*)d_in[3];
    const float* rel   = (const float*)d_in[4];
    const float* rot   = (const float*)d_in[5];
    float* ws  = (float*)d_ws;
    float* qkv = ws;
    float* bsb = ws + 602112;
    float* Rb  = ws + 870912;
    float* xT  = Rb;                 // aliases Rb; dead once k3 writes Rb
    int*   idx = (int*)(ws + 5171712);

    k0_xT<<<dim3(2, 56), 256, 0, stream>>>(x, xT);
    k12_qkv_sort<<<112, 256, 0, stream>>>(xT, cw, gamma, beta, rot, qkv, idx);
    k3_attn<<<dim3(112, 4, 3), 256, 0, stream>>>(qkv, idx, rel, Rb, bsb);
    k45_post<<<dim3(112, 2), 512, 0, stream>>>(Rb, bsb, idx, (float*)d_out);
}

// Round 7
// 140.941 us; speedup vs baseline: 2.2865x; 1.0693x over previous
//
#include <hip/hip_runtime.h>
#include <math.h>

// ============================================================================
// Sizes (fixed): N=2, C=64, Hax=56, W=56 -> B=112, H=56, OUT=64, N_HASHES=4,
// CHUNK=25, GROUPS=8, GP=8, hash_buckets=2, padding=19, K=3, qkv ch=96.
// Inputs fp32; OUTPUT FP32; stable argsort (established R8-R11).
// R20: 150.7us total. k3 profile artifact suspected (identical code/counters
//      as R17's 55.5us but 87us wall; VALU busy-time identical 25us) -->
//      k3 is LATENCY-bound: VALUBusy<=46%, HBM<=5%, ~16 waves/CU.
// R21: k3 at 512 threads; main loop split across lane PAIRS (j=2*jt+half,
//      38 serial iters instead of 75), combine via 17x shfl_xor(.,1);
//      uniform runtime-j loop (no divergent halves) enabled by relL in LDS
//      (2.7KB) + ks/jj via compares; LOG2E folded into DIT; DI 375thr x 5j;
//      gather/fold stride 512. LDS 43.1KB. k0/k12/k45 unchanged.
//
// ws layout (float slots):
//   qkv : [112][5376]   off 0
//   bsb : [112][2400]   off 602112
//   Rb  : [112][38400]  off 870912  (xT[2][56][56][64] aliases this pre-k3)
//   idx : [112][224]    off 5171712 (int)
// ============================================================================

#define EPSN 5e-5f
#define INV_EPSN 20000.0f
#define LOG2E 1.4426950408889634f
#define LN2   0.6931471805599453f

__device__ __forceinline__ float dot4(const float4 a, const float4 b) {
    return a.x * b.x + a.y * b.y + a.z * b.z + a.w * b.w;
}
__device__ __forceinline__ void fma4(float4& a, float s, const float4 v) {
    a.x += s * v.x; a.y += s * v.y; a.z += s * v.z; a.w += s * v.w;
}

// ---------------- K0: x[n][c][h][w] -> xT[n][h][w][c] (LDS transpose) ------
__global__ __launch_bounds__(256) void k0_xT(
        const float* __restrict__ x, float* __restrict__ xT) {
    __shared__ float T[64][57];                 // pad 57: conflict-free read
    const int n = blockIdx.x, h = blockIdx.y, tid = threadIdx.x;
    const float* xb = x + n * 200704 + h * 56;
    #pragma unroll 7
    for (int i = tid; i < 3584; i += 256) {     // lanes: consecutive w
        int c = i / 56, w = i % 56;
        T[c][w] = xb[c * 3136 + w];
    }
    __syncthreads();
    float* xo = xT + n * 200704 + h * 3584;
    #pragma unroll 7
    for (int i = tid; i < 3584; i += 256) {     // lanes: consecutive c
        int w = i / 64, c = i % 64;
        xo[w * 64 + c] = T[c][w];
    }
}

// ---------------- K12: qkv GEMM + BN + LSH codes + stable argsort ----------
// Staging reads xT coalesced (float4). o-quad register tile.
__global__ __launch_bounds__(256) void k12_qkv_sort(
        const float* __restrict__ xT, const float* __restrict__ cw,
        const float* __restrict__ gamma, const float* __restrict__ beta,
        const float* __restrict__ rot, float* __restrict__ qkv,
        int* __restrict__ idx_buf) {
    __shared__ float xsT[56 * 68];   // [h][c], pad 64->68
    __shared__ float cws[96 * 64];
    __shared__ float wm[56 * 32];    // w_match[t][f]
    __shared__ float rl[128];
    __shared__ float gs[96], bt[96];
    __shared__ int code[224];
    __shared__ int srt[224];
    const int b = blockIdx.x, n = b / 56, w = b % 56, tid = threadIdx.x;
    const float* xTb = xT + n * 200704 + w * 64;
    #pragma unroll 4
    for (int i = tid; i < 896; i += 256) {      // coalesced float4 rows
        int h = i / 16, cq = i % 16;
        *(float4*)&xsT[h * 68 + cq * 4] =
            *(const float4*)&xTb[h * 3584 + cq * 4];
    }
    #pragma unroll 8
    for (int i = tid; i < 6144; i += 256) cws[i] = cw[i];
    if (tid < 128) rl[tid] = rot[tid];
    if (tid < 96) { gs[tid] = gamma[tid]; bt[tid] = beta[tid]; }
    __syncthreads();
    const float inv_s = 1.0f / sqrtf(1.0f + 1.0e-5f);
    for (int tl = tid; tl < 1344; tl += 256) {
        int oq = tl / 56, h = tl % 56;
        int o0 = oq * 4;
        float s0 = 0.f, s1 = 0.f, s2 = 0.f, s3 = 0.f;
        #pragma unroll
        for (int cs = 0; cs < 16; ++cs) {
            float4 xv = *(const float4*)&xsT[h * 68 + cs * 4];
            float4 c0 = *(const float4*)&cws[(o0 + 0) * 64 + cs * 4];
            float4 c1 = *(const float4*)&cws[(o0 + 1) * 64 + cs * 4];
            float4 c2 = *(const float4*)&cws[(o0 + 2) * 64 + cs * 4];
            float4 c3 = *(const float4*)&cws[(o0 + 3) * 64 + cs * 4];
            s0 += dot4(xv, c0); s1 += dot4(xv, c1);
            s2 += dot4(xv, c2); s3 += dot4(xv, c3);
        }
        #pragma unroll
        for (int qq = 0; qq < 4; ++qq) {
            int o = o0 + qq;
            float sv = (qq == 0) ? s0 : (qq == 1) ? s1 : (qq == 2) ? s2 : s3;
            float val = sv * inv_s * gs[o] + bt[o];
            int j = o * 56 + h;
            qkv[b * 5376 + j] = val;
            int f = j % 96;                      // raw (B,96,56)->(B,56,96)
            if (f < 32) wm[(j / 96) * 32 + f] = val;
        }
    }
    __syncthreads();
    if (tid < 224) {
        int u = tid / 56, t = tid % 56;
        float s = 0.f;
        #pragma unroll 8
        for (int f = 0; f < 32; ++f) s += wm[t * 32 + f] * rl[f * 4 + u];
        code[tid] = ((s < 0.f) ? 1 : 0) + 2 * u;
    }
    __syncthreads();
    if (tid < 224) {
        int c = code[tid], r = 0;
        #pragma unroll 8
        for (int p = 0; p < 224; ++p) {
            int cp = code[p];
            r += (int)((cp < c) | ((cp == c) & (p < tid)));  // stable rank
        }
        srt[r] = tid;
    }
    __syncthreads();
    if (tid < 224) idx_buf[b * 224 + tid] = srt[tid];
}

// ---------------- K3: chunked attention, one block per (b,u,k), 512 thr ----
// Phases: ibL+relL stage -> gather/normalize -> DI (375thr x 5j, DIT holds
// di*LOG2E) -> fold 0.1*we into Wc -> main split across lane pairs
// (j = 2*jt + half; 38 serial iters; combine via shfl_xor 1). LDS 43.1KB.
__global__ __launch_bounds__(512) void k3_attn(
        const float* __restrict__ qkv, const int* __restrict__ idx_buf,
        const float* __restrict__ rel, float* __restrict__ Rb,
        float* __restrict__ bsb) {
    __shared__ __align__(16) float Wc[8][3][25][4];   // normalized, then +0.1*we
    __shared__ __align__(16) float Vb[8][3][25][8];
    __shared__ __align__(16) float WbK[8][25][4];     // raw w_b at kk==k
    __shared__ float DIT[75][25];                     // di * LOG2E, transposed
    __shared__ __align__(16) float relL[672];         // rel[56][12] staged
    __shared__ int ibL[224];
    const int b = blockIdx.x, u = blockIdx.y, k = blockIdx.z;
    const int tid = threadIdx.x;
    const float* q = qkv + b * 5376;

    if (tid < 224) ibL[tid] = idx_buf[b * 224 + tid];
    for (int i2 = tid; i2 < 672; i2 += 512) relL[i2] = rel[i2];
    __syncthreads();

    #pragma unroll 2
    for (int idx = tid; idx < 600; idx += 512) {
        int i = idx % 25, kk = (idx / 25) % 3, g = idx / 75;
        int p0 = 1200 * g + 300 * u + 100 * kk + 4 * i;
        int h = p0 / 2400, r = p0 % 2400, t = r >> 5, f = r & 31;
        int row = (t < 56) ? t : t - 19;
        int tt = ibL[h * 56 + row] % 56;
        float4 v = *(const float4*)&q[tt * 96 + f];
        if (kk == k) *(float4*)&WbK[g][i][0] = v;
        float ni = fminf(__builtin_amdgcn_rsqf(dot4(v, v)), INV_EPSN);
        v.x *= ni; v.y *= ni; v.z *= ni; v.w *= ni;
        *(float4*)&Wc[g][kk][i][0] = v;
    }
    #pragma unroll 3
    for (int idx = tid; idx < 1200; idx += 512) {
        int half = idx & 1, fr = idx >> 1;
        int i = fr % 25, kk = (fr / 25) % 3, g = fr / 75;
        int p0 = 2400 * g + 600 * u + 200 * kk + 8 * i + 4 * half;
        int h = p0 / 4800, r = p0 % 4800, t = r >> 6, f = r & 63;
        int row = (t < 56) ? t : t - 19;
        int tt = ibL[h * 56 + row] % 56;
        *(float4*)&Vb[g][kk][i][4 * half] = *(const float4*)&q[tt * 96 + 32 + f];
    }
    __syncthreads();

    // DI phase: 375 threads x 5 j's; register wb8; DIT[j][i] = di*LOG2E.
    if (tid < 375) {
        const int i = tid % 25, jg = tid / 25;    // jg 0..14
        float4 wb8[8];
        #pragma unroll
        for (int g = 0; g < 8; ++g) wb8[g] = *(const float4*)&WbK[g][i][0];
        #pragma unroll
        for (int it = 0; it < 5; ++it) {
            int j = jg * 5 + it;
            int ks = (j >= 25) + (j >= 50), jj = j - ks * 25;
            int roww = (j < 56) ? j : j - 19;
            float4 we = *(const float4*)&relL[roww * 12];
            we.x *= 0.1f; we.y *= 0.1f; we.z *= 0.1f; we.w *= 0.1f;
            float s2 = 0.f;
            #pragma unroll
            for (int g = 0; g < 8; ++g) {
                float4 wcn = *(const float4*)&Wc[g][ks][jj][0];
                float raw = dot4(wb8[g], wcn);
                float emb = dot4(wb8[g], we);
                s2 += raw * raw + emb * emb;
            }
            DIT[j][i] = fminf(__builtin_amdgcn_rsqf(s2), INV_EPSN) * LOG2E;
        }
    }
    __syncthreads();

    // Fold 0.1*we into Wc so main loop is one dot4 per (g,j).
    #pragma unroll 2
    for (int idx = tid; idx < 600; idx += 512) {
        int i = idx % 25, kk = (idx / 25) % 3, g = idx / 75;
        int tw = kk * 25 + i;
        int roww = (tw < 56) ? tw : tw - 19;
        float4 we = *(const float4*)&relL[roww * 12];
        float4 v = *(const float4*)&Wc[g][kk][i][0];
        v.x += 0.1f * we.x; v.y += 0.1f * we.y;
        v.z += 0.1f * we.z; v.w += 0.1f * we.w;
        *(float4*)&Wc[g][kk][i][0] = v;
    }
    __syncthreads();

    // Main: lane pairs (2p, 2p+1) split j's; 38 serial iters each.
    if (tid < 400) {
        const int half = tid & 1, gi = tid >> 1;  // gi 0..199
        const int g = gi & 7, i = gi >> 3;
        const float4 wbr = *(const float4*)&WbK[g][i][0];
        float se = 0.f;
        float4 a0 = {0,0,0,0}, a1 = {0,0,0,0}, a2 = {0,0,0,0}, a3 = {0,0,0,0};
        #pragma unroll 4
        for (int jt = 0; jt < 38; ++jt) {
            int j = jt * 2 + half;                // half0: even<=74; half1: odd<=75
            if (j < 75) {
                int ks = (j >= 25) + (j >= 50), jj = j - ks * 25;
                int roww = (j < 56) ? j : j - 19;
                float e = __builtin_amdgcn_exp2f(
                    dot4(wbr, *(const float4*)&Wc[g][ks][jj][0]) * DIT[j][i]);
                se += e;
                const float4* vv = (const float4*)&Vb[g][ks][jj][0];
                fma4(a0, e, vv[0]); fma4(a1, e, vv[1]);
                float4 ve0 = *(const float4*)&relL[roww * 12 + 4];
                float4 ve1 = *(const float4*)&relL[roww * 12 + 8];
                fma4(a2, e, ve0); fma4(a3, e, ve1);
            }
        }
        // combine pair partials (adjacent lanes, same wave)
        se += __shfl_xor(se, 1);
        a0.x += __shfl_xor(a0.x, 1); a0.y += __shfl_xor(a0.y, 1);
        a0.z += __shfl_xor(a0.z, 1); a0.w += __shfl_xor(a0.w, 1);
        a1.x += __shfl_xor(a1.x, 1); a1.y += __shfl_xor(a1.y, 1);
        a1.z += __shfl_xor(a1.z, 1); a1.w += __shfl_xor(a1.w, 1);
        a2.x += __shfl_xor(a2.x, 1); a2.y += __shfl_xor(a2.y, 1);
        a2.z += __shfl_xor(a2.z, 1); a2.w += __shfl_xor(a2.w, 1);
        a3.x += __shfl_xor(a3.x, 1); a3.y += __shfl_xor(a3.y, 1);
        a3.z += __shfl_xor(a3.z, 1); a3.w += __shfl_xor(a3.w, 1);
        if (half == 0) {
            bsb[b * 2400 + g * 300 + u * 75 + k * 25 + i] =
                __builtin_amdgcn_logf(se) * LN2;          // logsumexp, no shift
            const float rinv = 1.0f / se;
            const float r2 = 0.1f * rinv;                 // F_GV1
            a0.x *= rinv; a0.y *= rinv; a0.z *= rinv; a0.w *= rinv;
            a1.x *= rinv; a1.y *= rinv; a1.z *= rinv; a1.w *= rinv;
            a2.x *= r2;   a2.y *= r2;   a2.z *= r2;   a2.w *= r2;
            a3.x *= r2;   a3.y *= r2;   a3.z *= r2;   a3.w *= r2;
            float* rp = Rb + b * 38400 + 4800 * g + 1200 * u + 400 * k + 16 * i;
            ((float4*)rp)[0] = a0;
            ((float4*)rp)[1] = a1;
            ((float4*)rp)[2] = a2;
            ((float4*)rp)[3] = a3;
        }
    }
}

// ---------------- K45: channel l2norm + bs-pass + unsort + hash softmax
//                        + transposed FP32 store. Split (b, o-half), 512 thr.
__global__ __launch_bounds__(512) void k45_post(
        const float* __restrict__ Rb, const float* __restrict__ bsb,
        const int* __restrict__ idx_buf, float* __restrict__ out) {
    __shared__ float D[300];
    __shared__ float bsn[300];
    __shared__ float retU[224][32];
    __shared__ float bsU[224];
    __shared__ int idxL[224];
    const int b = blockIdx.x, oh = blockIdx.y, tid = threadIdx.x;
    const int n = b / 56, w = b % 56, o0 = oh * 32;
    const float* R = Rb + b * 38400;
    if (tid < 224) idxL[tid] = idx_buf[b * 224 + tid];
    if (tid < 300) {
        float s = 0.f;
        #pragma unroll 16
        for (int c = 0; c < 128; ++c) { float v = R[c * 300 + tid]; s += v * v; }
        D[tid] = fminf(__builtin_amdgcn_rsqf(s), INV_EPSN);
    }
    if (tid < 300) {
        int u = tid / 75, t = tid % 75;
        float s2 = 0.f, sum = 0.f;
        #pragma unroll
        for (int g = 0; g < 8; ++g) {
            float v = bsb[b * 2400 + g * 300 + u * 75 + t];
            s2 += v * v; sum += v;
        }
        bsn[tid] = sum / fmaxf(sqrtf(s2), EPSN);
    }
    __syncthreads();
    if (tid < 224) {
        int u3 = tid / 56, t = tid % 56;
        bsU[idxL[tid]] = bsn[u3 * 75 + t];
    }
    #pragma unroll 4
    for (int idx = tid; idx < 224 * 32; idx += 512) {
        int p = idx >> 5, oc = idx & 31;
        int o = o0 + oc;
        int u3 = p / 56, t = p % 56;
        int k3 = t / 25, i3 = t % 25;
        int q0 = 9600 * u3 + 3200 * k3 + 128 * i3 + 2 * o;
        float2 rv = *(const float2*)&R[q0];
        int r0 = q0 % 300;                       // q0 even => r0+1 never wraps
        float val = rv.x * D[r0] + rv.y * D[r0 + 1];
        retU[idxL[p]][oc] = val;
    }
    __syncthreads();
    for (int idx = tid; idx < 56 * 32; idx += 512) {
        int h = idx >> 5, oc = idx & 31;
        int o = o0 + oc;
        float b0 = bsU[h], b1 = bsU[56 + h], b2 = bsU[112 + h], b3 = bsU[168 + h];
        float m = fmaxf(fmaxf(b0, b1), fmaxf(b2, b3));
        float e0 = __builtin_amdgcn_exp2f((b0 - m) * LOG2E);
        float e1 = __builtin_amdgcn_exp2f((b1 - m) * LOG2E);
        float e2 = __builtin_amdgcn_exp2f((b2 - m) * LOG2E);
        float e3 = __builtin_amdgcn_exp2f((b3 - m) * LOG2E);
        float ps = e0 + e1 + e2 + e3;
        float val = (retU[h][oc] * e0 + retU[56 + h][oc] * e1 +
                     retU[112 + h][oc] * e2 + retU[168 + h][oc] * e3) / ps;
        out[((n * 64 + o) * 56 + h) * 56 + w] = val;   // (n,o,h,w)
    }
}

extern "C" void kernel_launch(void* const* d_in, const int* in_sizes, int n_in,
                              void* d_out, int out_size, void* d_ws, size_t ws_size,
                              hipStream_t stream) {
    (void)in_sizes; (void)n_in; (void)out_size; (void)ws_size;
    const float* x     = (const float*)d_in[0];
    const float* cw    = (const float*)d_in[1];
    const float* gamma = (const float*)d_in[2];
    const float* beta  = (const float*)d_in[3];
    const float* rel   = (const float*)d_in[4];
    const float* rot   = (const float*)d_in[5];
    float* ws  = (float*)d_ws;
    float* qkv = ws;
    float* bsb = ws + 602112;
    float* Rb  = ws + 870912;
    float* xT  = Rb;                 // aliases Rb; dead once k3 writes Rb
    int*   idx = (int*)(ws + 5171712);

    k0_xT<<<dim3(2, 56), 256, 0, stream>>>(x, xT);
    k12_qkv_sort<<<112, 256, 0, stream>>>(xT, cw, gamma, beta, rot, qkv, idx);
    k3_attn<<<dim3(112, 4, 3), 512, 0, stream>>>(qkv, idx, rel, Rb, bsb);
    k45_post<<<dim3(112, 2), 512, 0, stream>>>(Rb, bsb, idx, (float*)d_out);
}